// Round 5
// baseline (147.069 us; speedup 1.0000x reference)
//
#include <hip/hip_runtime.h>

#define BB 64
#define C1 3
#define LIN 8192
#define PAD1 2
#define O1 6
#define KK1 80
#define LP1 4058       // pooled length after conv1(pad=2,K=80) + avgpool2

#define O2 16
#define KK2 3
#define LP2 2028

#define NFLAT 32448    // 16*2028 = 507*64
#define H1 120
#define H2 84
#define NOUT 10

typedef _Float16 h2 __attribute__((ext_vector_type(2)));
typedef _Float16 f16x8 __attribute__((ext_vector_type(8)));
typedef float f32x4 __attribute__((ext_vector_type(4)));
#define BIGH ((_Float16)30000.0f)

__device__ __forceinline__ h2 bch2(float f) { return __builtin_bit_cast(h2, f); }

// Guaranteed-packed fp16 ops (VOP3P). If the compiler already packs, these are
// the identical instructions; if it was splitting into 2x v_min_f16, this halves
// the VALU stream of the conv1 inner loop.
__device__ __forceinline__ h2 pkadd(h2 a, h2 b) {
  h2 d; asm("v_pk_add_f16 %0, %1, %2" : "=v"(d) : "v"(a), "v"(b)); return d;
}
__device__ __forceinline__ h2 pkmin(h2 a, h2 b) {
  h2 d; asm("v_pk_min_f16 %0, %1, %2" : "=v"(d) : "v"(a), "v"(b)); return d;
}

// ---------------- Kernel 0: pack w1 into half2 pairs (w[2m], w[2m+1]) ----------------
__global__ __launch_bounds__(256) void k_prep(const float* __restrict__ w1,
                                              float* __restrict__ whb) {
  const int idx = threadIdx.x + blockIdx.x * 256;
  if (idx >= (O1 * C1) * (KK1 / 2)) return;
  const int oc = idx / (KK1 / 2);
  const int m  = idx - oc * (KK1 / 2);
  h2 v;
  v.x = (_Float16)w1[oc * KK1 + 2 * m];
  v.y = (_Float16)w1[oc * KK1 + 2 * m + 1];
  whb[idx] = __builtin_bit_cast(float, v);
}

// ---------------- Kernel 1: FUSED tropical conv1(min)+pool2 -> conv2(max)+pool2 ----------
// v4: revert to 256-thread/TILE2=127 (v3's 128-thread split regressed 40->48us,
// occupancy pinned at 25% either way). launch_bounds(256,2) lifts the VGPR cap
// (was 64) so the compiler can pipeline the wave-uniform weight loads deeper;
// mc-loop fully unrolled; packed min/add forced via asm.
#define TILE2 127
#define NT12 16
#define DW12 295      // staged x pair-count: max read elem idx 2*(255+36)+7 = 589 = 2*294+1

__global__ __launch_bounds__(256, 2) void k_conv12(const float* __restrict__ x,
                                                   const float* __restrict__ whb,
                                                   const float* __restrict__ w2,
                                                   _Float16* __restrict__ p2h) {
  __shared__ float AB[C1][2 * DW12 + 2];
  __shared__ float ps[O1][256];
  __shared__ float w2s[O2 * O1 * KK2];   // 288 floats
  const int tile = blockIdx.x;           // 0..15
  const int b    = blockIdx.y;           // 0..63
  const int pj0  = 2 * TILE2 * tile;     // pooled-conv1 base index (254*tile)
  const int T0   = 2 * pj0;              // x-domain base
  const int tid  = threadIdx.x;

  for (int idx = tid; idx < O2 * O1 * KK2; idx += 256) w2s[idx] = w2[idx];
  for (int q = tid; q < C1 * DW12; q += 256) {
    const int c = q / DW12;
    const int d = q - c * DW12;
    const int E = T0 + 2 * d - PAD1;
    const float* xc = x + ((size_t)b * C1 + c) * LIN;
    float f0 = 0.f, f1 = 0.f, f2 = 0.f;
    if ((unsigned)E < LIN) f0 = xc[E];
    if ((unsigned)(E + 1) < LIN) f1 = xc[E + 1];
    if ((unsigned)(E + 2) < LIN) f2 = xc[E + 2];
    h2 A; A.x = (_Float16)f0; A.y = (_Float16)f1;
    h2 Bv; Bv.x = (_Float16)f1; Bv.y = (_Float16)f2;
    AB[c][2 * d]     = __builtin_bit_cast(float, A);
    AB[c][2 * d + 1] = __builtin_bit_cast(float, Bv);
  }
  __syncthreads();

  // ---- conv1 (min-plus) + avgpool2 for pooled position pj0 + jj ----
  const int jj = tid;

  float s0 = 0.f, s1 = 0.f, s2 = 0.f, s3 = 0.f, s4 = 0.f, s5 = 0.f;

#pragma unroll
  for (int c = 0; c < C1; ++c) {
    h2 aA[O1], aB[O1];
#pragma unroll
    for (int o = 0; o < O1; ++o) {
      aA[o].x = BIGH; aA[o].y = BIGH;
      aB[o].x = BIGH; aB[o].y = BIGH;
    }
#pragma unroll
    for (int mc = 0; mc < 10; ++mc) {      // m = mc*4 .. mc*4+3
      float4 xv0 = *(const float4*)&AB[c][2 * (jj + mc * 4)];
      float4 xv1 = *(const float4*)&AB[c][2 * (jj + mc * 4) + 4];
      h2 A0 = bch2(xv0.x), B0 = bch2(xv0.y);
      h2 A1 = bch2(xv0.z), B1 = bch2(xv0.w);
      h2 A2 = bch2(xv1.x), B2 = bch2(xv1.y);
      h2 A3 = bch2(xv1.z), B3 = bch2(xv1.w);
#pragma unroll
      for (int o = 0; o < O1; ++o) {
        float4 wq = *(const float4*)&whb[(o * C1 + c) * (KK1 / 2) + mc * 4];
        h2 w0 = bch2(wq.x), w1v = bch2(wq.y), w2v = bch2(wq.z), w3v = bch2(wq.w);
        aA[o] = pkmin(aA[o], pkadd(A0, w0));
        aB[o] = pkmin(aB[o], pkadd(B0, w0));
        aA[o] = pkmin(aA[o], pkadd(A1, w1v));
        aB[o] = pkmin(aB[o], pkadd(B1, w1v));
        aA[o] = pkmin(aA[o], pkadd(A2, w2v));
        aB[o] = pkmin(aB[o], pkadd(B2, w2v));
        aA[o] = pkmin(aA[o], pkadd(A3, w3v));
        aB[o] = pkmin(aB[o], pkadd(B3, w3v));
      }
    }
    float r[O1];
#pragma unroll
    for (int o = 0; o < O1; ++o)
      r[o] = fminf((float)aA[o].x, (float)aA[o].y) + fminf((float)aB[o].x, (float)aB[o].y);
    s0 += r[0]; s1 += r[1]; s2 += r[2]; s3 += r[3]; s4 += r[4]; s5 += r[5];
  }
  ps[0][jj] = 0.5f * s0;
  ps[1][jj] = 0.5f * s1;
  ps[2][jj] = 0.5f * s2;
  ps[3][jj] = 0.5f * s3;
  ps[4][jj] = 0.5f * s4;
  ps[5][jj] = 0.5f * s5;
  __syncthreads();

  // ---- conv2 (max-plus, K=3) + avgpool2, straight from LDS ----
  const int j2i = tid & 127;             // local conv2 output
  const int ot  = tid >> 7;              // 0/1 -> o-range split
  const int j2  = TILE2 * tile + j2i;
  if (j2i < TILE2 && j2 < LP2) {
    const int lb = 2 * j2i;              // <= 252, +3 <= 255: in range
    float xv[O1][4];
#pragma unroll
    for (int c = 0; c < O1; ++c) {
      xv[c][0] = ps[c][lb];     xv[c][1] = ps[c][lb + 1];
      xv[c][2] = ps[c][lb + 2]; xv[c][3] = ps[c][lb + 3];
    }
#pragma unroll
    for (int oi = 0; oi < 8; ++oi) {
      const int o = ot * 8 + oi;
      float s = 0.f;
#pragma unroll
      for (int c = 0; c < O1; ++c) {
        float w0  = w2s[(o * O1 + c) * KK2 + 0];
        float w1v = w2s[(o * O1 + c) * KK2 + 1];
        float w2v = w2s[(o * O1 + c) * KK2 + 2];
        float m0 = fmaxf(fmaxf(xv[c][0] + w0, xv[c][1] + w1v), xv[c][2] + w2v);
        float m1 = fmaxf(fmaxf(xv[c][1] + w0, xv[c][2] + w1v), xv[c][3] + w2v);
        s += m0 + m1;
      }
      p2h[(size_t)b * NFLAT + o * LP2 + j2] = (_Float16)(0.5f * s);
    }
  }
}

// ---------------- Kernel 2: FC1 split-K via MFMA f16, KC=128, 512 threads ----------------
// LDS XOR swizzle (half-index ^= (row&7)<<3): kills the 16-way bank conflict the
// row-stride-256B layout had on ds_read_b128 (G4/T2). Applied on BOTH write and read.
#define KC2 128
#define NKC2 254
#define BSWZ(row, colh) ((colh) ^ (((row) & 7) << 3))

#define FC1_STEP(ks)                                                                     \
  {                                                                                      \
    float4 al = *(const float4*)(wp + (ks) * 32);                                        \
    float4 ah = *(const float4*)(wp + (ks) * 32 + 4);                                    \
    f16x8 A;                                                                             \
    A[0] = (_Float16)al.x; A[1] = (_Float16)al.y;                                        \
    A[2] = (_Float16)al.z; A[3] = (_Float16)al.w;                                        \
    A[4] = (_Float16)ah.x; A[5] = (_Float16)ah.y;                                        \
    A[6] = (_Float16)ah.z; A[7] = (_Float16)ah.w;                                        \
    _Pragma("unroll")                                                                    \
    for (int nt = 0; nt < 4; ++nt) {                                                     \
      const int brow = nt * 16 + m_l;                                                    \
      f16x8 Bf = *(const f16x8*)&bs[brow][BSWZ(brow, (ks) * 32 + q * 8)];                \
      acc[nt] = __builtin_amdgcn_mfma_f32_16x16x32_f16(A, Bf, acc[nt], 0, 0, 0);         \
    }                                                                                    \
  }

__global__ __launch_bounds__(512) void k_fc1(const _Float16* __restrict__ p2h,
                                             const float* __restrict__ w,
                                             _Float16* __restrict__ part) {
  __shared__ _Float16 bs[64][KC2];    // [b][k] swizzled, 16 KB
  const int kc  = blockIdx.x;
  const int k0  = kc * KC2;
  const int tid = threadIdx.x;

  // stage: 64 rows x 16 float4 = 1024 tasks, 2 per thread; zero-pad K tail
#pragma unroll
  for (int r = 0; r < 2; ++r) {
    const int task = tid + 512 * r;
    const int row  = task >> 4;          // 0..63
    const int c4   = task & 15;          // 0..15
    const int k    = k0 + c4 * 8;
    float4 v = {0.f, 0.f, 0.f, 0.f};
    if (k + 8 <= NFLAT) v = *(const float4*)&p2h[(size_t)row * NFLAT + k];
    *(float4*)&bs[row][BSWZ(row, c4 * 8)] = v;
  }
  __syncthreads();

  const int lane = tid & 63;
  const int wid  = tid >> 6;             // 0..7
  const int m_l  = lane & 15;
  const int q    = lane >> 4;            // 0..3
  const int m0   = wid * 16;

  int rowA = m0 + m_l;                   // 0..127; clamp pad rows
  if (rowA > H1 - 1) rowA = H1 - 1;
  const float* wp = w + (size_t)rowA * NFLAT + k0 + q * 8;

  f32x4 acc[4];
#pragma unroll
  for (int nt = 0; nt < 4; ++nt) acc[nt] = (f32x4){0.f, 0.f, 0.f, 0.f};

  if (k0 + KC2 <= NFLAT) {
    FC1_STEP(0) FC1_STEP(1) FC1_STEP(2) FC1_STEP(3)
  } else {                               // last block: only 64 valid k
    FC1_STEP(0) FC1_STEP(1)
  }

#pragma unroll
  for (int nt = 0; nt < 4; ++nt)
#pragma unroll
    for (int r = 0; r < 4; ++r) {
      const int i = m0 + q * 4 + r;
      if (i < H1)
        part[((size_t)kc * H1 + i) * 64 + nt * 16 + m_l] = (_Float16)acc[nt][r];
    }
}

// ---------------- Kernel 3: reduce ALL partials + bias + ReLU -> h1[120][64] ----------
__global__ __launch_bounds__(1024) void k_h1(const _Float16* __restrict__ part,
                                             const float* __restrict__ fc1_b,
                                             float* __restrict__ h1g) {
  __shared__ float red[1024];
  const int i   = blockIdx.x;            // 0..119
  const int tid = threadIdx.x;
  const int b   = tid & 63;
  const int sub = tid >> 6;              // 0..15
  float acc = 0.f;
  for (int kc = sub; kc < NKC2; kc += 16)
    acc += (float)part[((size_t)kc * H1 + i) * 64 + b];
  red[tid] = acc;
  __syncthreads();
  if (tid < 64) {
    float t = 0.f;
#pragma unroll
    for (int s2 = 0; s2 < 16; ++s2) t += red[b + 64 * s2];
    h1g[i * 64 + b] = fmaxf(t + fc1_b[i], 0.f);
  }
}

// ---------------- Kernel 4: FC2+ReLU, FC3 ----------------
__global__ __launch_bounds__(128) void k_head(const float* __restrict__ h1g,
                                              const float* __restrict__ fc2_w,
                                              const float* __restrict__ fc2_b,
                                              const float* __restrict__ fc3_w,
                                              const float* __restrict__ fc3_b,
                                              float* __restrict__ out) {
  __shared__ float h1s[H1];
  __shared__ float h2s[H2];
  const int b = blockIdx.x;
  const int tid = threadIdx.x;
  if (tid < H1) h1s[tid] = h1g[tid * 64 + b];
  __syncthreads();
  if (tid < H2) {
    float s = fc2_b[tid];
#pragma unroll 4
    for (int n = 0; n < H1; ++n) s += h1s[n] * fc2_w[tid * H1 + n];
    h2s[tid] = fmaxf(s, 0.f);
  }
  __syncthreads();
  if (tid < NOUT) {
    float s = fc3_b[tid];
#pragma unroll 4
    for (int n = 0; n < H2; ++n) s += h2s[n] * fc3_w[tid * H2 + n];
    out[b * NOUT + tid] = s;
  }
}

extern "C" void kernel_launch(void* const* d_in, const int* in_sizes, int n_in,
                              void* d_out, int out_size, void* d_ws, size_t ws_size,
                              hipStream_t stream) {
  const float* x     = (const float*)d_in[0];
  const float* w1    = (const float*)d_in[1];
  const float* w2    = (const float*)d_in[2];
  const float* fc1_w = (const float*)d_in[3];
  const float* fc1_b = (const float*)d_in[4];
  const float* fc2_w = (const float*)d_in[5];
  const float* fc2_b = (const float*)d_in[6];
  const float* fc3_w = (const float*)d_in[7];
  const float* fc3_b = (const float*)d_in[8];

  _Float16* p2h  = (_Float16*)d_ws;                               // 64*32448 h
  _Float16* part = p2h + (size_t)BB * NFLAT;                      // 254*120*64 h
  float*    h1g  = (float*)(part + (size_t)NKC2 * H1 * 64);       // 120*64 f
  float*    whb  = h1g + (size_t)H1 * 64;                         // 720 f
  float*    out  = (float*)d_out;

  hipLaunchKernelGGL(k_prep, dim3(3), dim3(256), 0, stream, w1, whb);
  hipLaunchKernelGGL(k_conv12, dim3(NT12, BB), dim3(256), 0, stream, x, whb, w2, p2h);
  hipLaunchKernelGGL(k_fc1, dim3(NKC2), dim3(512), 0, stream, p2h, fc1_w, part);
  hipLaunchKernelGGL(k_h1, dim3(H1), dim3(1024), 0, stream, part, fc1_b, h1g);
  hipLaunchKernelGGL(k_head, dim3(BB), dim3(128), 0, stream, h1g, fc2_w, fc2_b,
                     fc3_w, fc3_b, out);
}

// Round 6
// 140.273 us; speedup vs baseline: 1.0484x; 1.0484x over previous
//
#include <hip/hip_runtime.h>

#define BB 64
#define C1 3
#define LIN 8192
#define PAD1 2
#define O1 6
#define KK1 80
#define LP1 4058       // pooled length after conv1(pad=2,K=80) + avgpool2

#define O2 16
#define KK2 3
#define LP2 2028

#define NFLAT 32448    // 16*2028 = 507*64
#define H1 120
#define H2 84
#define NOUT 10

typedef _Float16 h2 __attribute__((ext_vector_type(2)));
typedef _Float16 f16x8 __attribute__((ext_vector_type(8)));
typedef float f32x4 __attribute__((ext_vector_type(4)));
#define BIGH ((_Float16)30000.0f)

__device__ __forceinline__ h2 bch2(float f) { return __builtin_bit_cast(h2, f); }

// ---------------- Kernel 0: pack w1 into half2 pairs (w[2m], w[2m+1]) ----------------
__global__ __launch_bounds__(256) void k_prep(const float* __restrict__ w1,
                                              float* __restrict__ whb) {
  const int idx = threadIdx.x + blockIdx.x * 256;
  if (idx >= (O1 * C1) * (KK1 / 2)) return;
  const int oc = idx / (KK1 / 2);
  const int m  = idx - oc * (KK1 / 2);
  h2 v;
  v.x = (_Float16)w1[oc * KK1 + 2 * m];
  v.y = (_Float16)w1[oc * KK1 + 2 * m + 1];
  whb[idx] = __builtin_bit_cast(float, v);
}

// ---------------- Kernel 1: FUSED tropical conv1(min)+pool2 -> conv2(max)+pool2 ----------
// v5: two pooled outputs per thread (jj, jj+256) from ONE weight-load stream.
// v2's inner-op form kept verbatim (generic ops so weights stay SGPR operands;
// round-4 asm "v" constraints forced s->v moves and regressed). Weight-load
// issue per output halves; 2 independent chains per acc hide VMEM latency.
#define TILE2 255
#define NT12 8
#define DW12 551      // staged x pair-count: max read elem idx 2*(511+36)+7 = 1101

__global__ __launch_bounds__(256) void k_conv12(const float* __restrict__ x,
                                                const float* __restrict__ whb,
                                                const float* __restrict__ w2,
                                                _Float16* __restrict__ p2h) {
  __shared__ float AB[C1][2 * DW12 + 2];   // 13.2 KB
  __shared__ float ps[O1][512];            // 12.3 KB
  __shared__ float w2s[O2 * O1 * KK2];     // 1.2 KB
  const int tile = blockIdx.x;             // 0..7
  const int b    = blockIdx.y;             // 0..63
  const int pj0  = 2 * TILE2 * tile;       // pooled base (510*tile)
  const int T0   = 2 * pj0;                // x-domain base (1020*tile)
  const int tid  = threadIdx.x;

  for (int idx = tid; idx < O2 * O1 * KK2; idx += 256) w2s[idx] = w2[idx];
  for (int q = tid; q < C1 * DW12; q += 256) {
    const int c = q / DW12;
    const int d = q - c * DW12;
    const int E = T0 + 2 * d - PAD1;
    const float* xc = x + ((size_t)b * C1 + c) * LIN;
    float f0 = 0.f, f1 = 0.f, f2 = 0.f;
    if ((unsigned)E < LIN) f0 = xc[E];
    if ((unsigned)(E + 1) < LIN) f1 = xc[E + 1];
    if ((unsigned)(E + 2) < LIN) f2 = xc[E + 2];
    h2 A; A.x = (_Float16)f0; A.y = (_Float16)f1;
    h2 Bv; Bv.x = (_Float16)f1; Bv.y = (_Float16)f2;
    AB[c][2 * d]     = __builtin_bit_cast(float, A);
    AB[c][2 * d + 1] = __builtin_bit_cast(float, Bv);
  }
  __syncthreads();

  // ---- conv1 (min-plus) + avgpool2 for pooled positions pj0+jj and pj0+jj+256 ----
  const int jj = tid;

  float s0 = 0.f, s1 = 0.f, s2 = 0.f, s3 = 0.f, s4 = 0.f, s5 = 0.f;
  float u0 = 0.f, u1 = 0.f, u2 = 0.f, u3 = 0.f, u4 = 0.f, u5 = 0.f;

#pragma unroll
  for (int c = 0; c < C1; ++c) {
    h2 aA[O1], aB[O1], cA[O1], cB[O1];
#pragma unroll
    for (int o = 0; o < O1; ++o) {
      aA[o].x = BIGH; aA[o].y = BIGH;
      aB[o].x = BIGH; aB[o].y = BIGH;
      cA[o].x = BIGH; cA[o].y = BIGH;
      cB[o].x = BIGH; cB[o].y = BIGH;
    }
#pragma unroll 2
    for (int mc = 0; mc < 10; ++mc) {      // m = mc*4 .. mc*4+3
      float4 xa0 = *(const float4*)&AB[c][2 * (jj + mc * 4)];
      float4 xa1 = *(const float4*)&AB[c][2 * (jj + mc * 4) + 4];
      float4 xb0 = *(const float4*)&AB[c][2 * (jj + 256 + mc * 4)];
      float4 xb1 = *(const float4*)&AB[c][2 * (jj + 256 + mc * 4) + 4];
      h2 A0 = bch2(xa0.x), B0 = bch2(xa0.y);
      h2 A1 = bch2(xa0.z), B1 = bch2(xa0.w);
      h2 A2 = bch2(xa1.x), B2 = bch2(xa1.y);
      h2 A3 = bch2(xa1.z), B3 = bch2(xa1.w);
      h2 C0 = bch2(xb0.x), D0 = bch2(xb0.y);
      h2 C1v = bch2(xb0.z), D1 = bch2(xb0.w);
      h2 C2 = bch2(xb1.x), D2 = bch2(xb1.y);
      h2 C3 = bch2(xb1.z), D3 = bch2(xb1.w);
#pragma unroll
      for (int o = 0; o < O1; ++o) {
        float4 wq = *(const float4*)&whb[(o * C1 + c) * (KK1 / 2) + mc * 4];
        h2 w0 = bch2(wq.x), w1v = bch2(wq.y), w2v = bch2(wq.z), w3v = bch2(wq.w);
        aA[o] = __builtin_elementwise_min(aA[o], A0 + w0);
        aB[o] = __builtin_elementwise_min(aB[o], B0 + w0);
        cA[o] = __builtin_elementwise_min(cA[o], C0 + w0);
        cB[o] = __builtin_elementwise_min(cB[o], D0 + w0);
        aA[o] = __builtin_elementwise_min(aA[o], A1 + w1v);
        aB[o] = __builtin_elementwise_min(aB[o], B1 + w1v);
        cA[o] = __builtin_elementwise_min(cA[o], C1v + w1v);
        cB[o] = __builtin_elementwise_min(cB[o], D1 + w1v);
        aA[o] = __builtin_elementwise_min(aA[o], A2 + w2v);
        aB[o] = __builtin_elementwise_min(aB[o], B2 + w2v);
        cA[o] = __builtin_elementwise_min(cA[o], C2 + w2v);
        cB[o] = __builtin_elementwise_min(cB[o], D2 + w2v);
        aA[o] = __builtin_elementwise_min(aA[o], A3 + w3v);
        aB[o] = __builtin_elementwise_min(aB[o], B3 + w3v);
        cA[o] = __builtin_elementwise_min(cA[o], C3 + w3v);
        cB[o] = __builtin_elementwise_min(cB[o], D3 + w3v);
      }
    }
#pragma unroll
    for (int o = 0; o < O1; ++o) {
      float ra = fminf((float)aA[o].x, (float)aA[o].y) + fminf((float)aB[o].x, (float)aB[o].y);
      float rc = fminf((float)cA[o].x, (float)cA[o].y) + fminf((float)cB[o].x, (float)cB[o].y);
      if (o == 0) { s0 += ra; u0 += rc; }
      if (o == 1) { s1 += ra; u1 += rc; }
      if (o == 2) { s2 += ra; u2 += rc; }
      if (o == 3) { s3 += ra; u3 += rc; }
      if (o == 4) { s4 += ra; u4 += rc; }
      if (o == 5) { s5 += ra; u5 += rc; }
    }
  }
  ps[0][jj] = 0.5f * s0;  ps[0][jj + 256] = 0.5f * u0;
  ps[1][jj] = 0.5f * s1;  ps[1][jj + 256] = 0.5f * u1;
  ps[2][jj] = 0.5f * s2;  ps[2][jj + 256] = 0.5f * u2;
  ps[3][jj] = 0.5f * s3;  ps[3][jj + 256] = 0.5f * u3;
  ps[4][jj] = 0.5f * s4;  ps[4][jj + 256] = 0.5f * u4;
  ps[5][jj] = 0.5f * s5;  ps[5][jj + 256] = 0.5f * u5;
  __syncthreads();

  // ---- conv2 (max-plus, K=3) + avgpool2, straight from LDS ----
  const int j2i = tid;                   // local conv2 output, 0..254 valid
  const int j2  = TILE2 * tile + j2i;
  if (j2i < TILE2 && j2 < LP2) {
    const int lb = 2 * j2i;              // <= 508, +3 <= 511: in range
    float xv[O1][4];
#pragma unroll
    for (int c = 0; c < O1; ++c) {
      xv[c][0] = ps[c][lb];     xv[c][1] = ps[c][lb + 1];
      xv[c][2] = ps[c][lb + 2]; xv[c][3] = ps[c][lb + 3];
    }
#pragma unroll
    for (int o = 0; o < O2; ++o) {
      float s = 0.f;
#pragma unroll
      for (int c = 0; c < O1; ++c) {
        float w0  = w2s[(o * O1 + c) * KK2 + 0];
        float w1v = w2s[(o * O1 + c) * KK2 + 1];
        float w2v = w2s[(o * O1 + c) * KK2 + 2];
        float m0 = fmaxf(fmaxf(xv[c][0] + w0, xv[c][1] + w1v), xv[c][2] + w2v);
        float m1 = fmaxf(fmaxf(xv[c][1] + w0, xv[c][2] + w1v), xv[c][3] + w2v);
        s += m0 + m1;
      }
      p2h[(size_t)b * NFLAT + o * LP2 + j2] = (_Float16)(0.5f * s);
    }
  }
}

// ---------------- Kernel 2: FC1 split-K via MFMA f16, KC=128, 512 threads ----------------
// LDS XOR swizzle (half-index ^= (row&7)<<3): kills the 16-way bank conflict the
// row-stride-256B layout had on ds_read_b128 (G4/T2). Applied on BOTH write and read.
#define KC2 128
#define NKC2 254
#define BSWZ(row, colh) ((colh) ^ (((row) & 7) << 3))

#define FC1_STEP(ks)                                                                     \
  {                                                                                      \
    float4 al = *(const float4*)(wp + (ks) * 32);                                        \
    float4 ah = *(const float4*)(wp + (ks) * 32 + 4);                                    \
    f16x8 A;                                                                             \
    A[0] = (_Float16)al.x; A[1] = (_Float16)al.y;                                        \
    A[2] = (_Float16)al.z; A[3] = (_Float16)al.w;                                        \
    A[4] = (_Float16)ah.x; A[5] = (_Float16)ah.y;                                        \
    A[6] = (_Float16)ah.z; A[7] = (_Float16)ah.w;                                        \
    _Pragma("unroll")                                                                    \
    for (int nt = 0; nt < 4; ++nt) {                                                     \
      const int brow = nt * 16 + m_l;                                                    \
      f16x8 Bf = *(const f16x8*)&bs[brow][BSWZ(brow, (ks) * 32 + q * 8)];                \
      acc[nt] = __builtin_amdgcn_mfma_f32_16x16x32_f16(A, Bf, acc[nt], 0, 0, 0);         \
    }                                                                                    \
  }

__global__ __launch_bounds__(512) void k_fc1(const _Float16* __restrict__ p2h,
                                             const float* __restrict__ w,
                                             _Float16* __restrict__ part) {
  __shared__ _Float16 bs[64][KC2];    // [b][k] swizzled, 16 KB
  const int kc  = blockIdx.x;
  const int k0  = kc * KC2;
  const int tid = threadIdx.x;

  // stage: 64 rows x 16 float4 = 1024 tasks, 2 per thread; zero-pad K tail
#pragma unroll
  for (int r = 0; r < 2; ++r) {
    const int task = tid + 512 * r;
    const int row  = task >> 4;          // 0..63
    const int c4   = task & 15;          // 0..15
    const int k    = k0 + c4 * 8;
    float4 v = {0.f, 0.f, 0.f, 0.f};
    if (k + 8 <= NFLAT) v = *(const float4*)&p2h[(size_t)row * NFLAT + k];
    *(float4*)&bs[row][BSWZ(row, c4 * 8)] = v;
  }
  __syncthreads();

  const int lane = tid & 63;
  const int wid  = tid >> 6;             // 0..7
  const int m_l  = lane & 15;
  const int q    = lane >> 4;            // 0..3
  const int m0   = wid * 16;

  int rowA = m0 + m_l;                   // 0..127; clamp pad rows
  if (rowA > H1 - 1) rowA = H1 - 1;
  const float* wp = w + (size_t)rowA * NFLAT + k0 + q * 8;

  f32x4 acc[4];
#pragma unroll
  for (int nt = 0; nt < 4; ++nt) acc[nt] = (f32x4){0.f, 0.f, 0.f, 0.f};

  if (k0 + KC2 <= NFLAT) {
    FC1_STEP(0) FC1_STEP(1) FC1_STEP(2) FC1_STEP(3)
  } else {                               // last block: only 64 valid k
    FC1_STEP(0) FC1_STEP(1)
  }

#pragma unroll
  for (int nt = 0; nt < 4; ++nt)
#pragma unroll
    for (int r = 0; r < 4; ++r) {
      const int i = m0 + q * 4 + r;
      if (i < H1)
        part[((size_t)kc * H1 + i) * 64 + nt * 16 + m_l] = (_Float16)acc[nt][r];
    }
}

// ---------------- Kernel 3: reduce ALL partials + bias + ReLU -> h1[120][64] ----------
__global__ __launch_bounds__(1024) void k_h1(const _Float16* __restrict__ part,
                                             const float* __restrict__ fc1_b,
                                             float* __restrict__ h1g) {
  __shared__ float red[1024];
  const int i   = blockIdx.x;            // 0..119
  const int tid = threadIdx.x;
  const int b   = tid & 63;
  const int sub = tid >> 6;              // 0..15
  float acc = 0.f;
  for (int kc = sub; kc < NKC2; kc += 16)
    acc += (float)part[((size_t)kc * H1 + i) * 64 + b];
  red[tid] = acc;
  __syncthreads();
  if (tid < 64) {
    float t = 0.f;
#pragma unroll
    for (int s2 = 0; s2 < 16; ++s2) t += red[b + 64 * s2];
    h1g[i * 64 + b] = fmaxf(t + fc1_b[i], 0.f);
  }
}

// ---------------- Kernel 4: FC2+ReLU, FC3 ----------------
__global__ __launch_bounds__(128) void k_head(const float* __restrict__ h1g,
                                              const float* __restrict__ fc2_w,
                                              const float* __restrict__ fc2_b,
                                              const float* __restrict__ fc3_w,
                                              const float* __restrict__ fc3_b,
                                              float* __restrict__ out) {
  __shared__ float h1s[H1];
  __shared__ float h2s[H2];
  const int b = blockIdx.x;
  const int tid = threadIdx.x;
  if (tid < H1) h1s[tid] = h1g[tid * 64 + b];
  __syncthreads();
  if (tid < H2) {
    float s = fc2_b[tid];
#pragma unroll 4
    for (int n = 0; n < H1; ++n) s += h1s[n] * fc2_w[tid * H1 + n];
    h2s[tid] = fmaxf(s, 0.f);
  }
  __syncthreads();
  if (tid < NOUT) {
    float s = fc3_b[tid];
#pragma unroll 4
    for (int n = 0; n < H2; ++n) s += h2s[n] * fc3_w[tid * H2 + n];
    out[b * NOUT + tid] = s;
  }
}

extern "C" void kernel_launch(void* const* d_in, const int* in_sizes, int n_in,
                              void* d_out, int out_size, void* d_ws, size_t ws_size,
                              hipStream_t stream) {
  const float* x     = (const float*)d_in[0];
  const float* w1    = (const float*)d_in[1];
  const float* w2    = (const float*)d_in[2];
  const float* fc1_w = (const float*)d_in[3];
  const float* fc1_b = (const float*)d_in[4];
  const float* fc2_w = (const float*)d_in[5];
  const float* fc2_b = (const float*)d_in[6];
  const float* fc3_w = (const float*)d_in[7];
  const float* fc3_b = (const float*)d_in[8];

  _Float16* p2h  = (_Float16*)d_ws;                               // 64*32448 h
  _Float16* part = p2h + (size_t)BB * NFLAT;                      // 254*120*64 h
  float*    h1g  = (float*)(part + (size_t)NKC2 * H1 * 64);       // 120*64 f
  float*    whb  = h1g + (size_t)H1 * 64;                         // 720 f
  float*    out  = (float*)d_out;

  hipLaunchKernelGGL(k_prep, dim3(3), dim3(256), 0, stream, w1, whb);
  hipLaunchKernelGGL(k_conv12, dim3(NT12, BB), dim3(256), 0, stream, x, whb, w2, p2h);
  hipLaunchKernelGGL(k_fc1, dim3(NKC2), dim3(512), 0, stream, p2h, fc1_w, part);
  hipLaunchKernelGGL(k_h1, dim3(H1), dim3(1024), 0, stream, part, fc1_b, h1g);
  hipLaunchKernelGGL(k_head, dim3(BB), dim3(128), 0, stream, h1g, fc2_w, fc2_b,
                     fc3_w, fc3_b, out);
}

// Round 7
// 135.714 us; speedup vs baseline: 1.0837x; 1.0336x over previous
//
#include <hip/hip_runtime.h>

#define BB 64
#define C1 3
#define LIN 8192
#define PAD1 2
#define O1 6
#define KK1 80
#define LP1 4058       // pooled length after conv1(pad=2,K=80) + avgpool2

#define O2 16
#define KK2 3
#define LP2 2028

#define NFLAT 32448    // 16*2028 = 507*64
#define H1 120
#define H2 84
#define NOUT 10

typedef _Float16 h2 __attribute__((ext_vector_type(2)));
typedef _Float16 f16x8 __attribute__((ext_vector_type(8)));
typedef float f32x4 __attribute__((ext_vector_type(4)));
#define BIGH ((_Float16)30000.0f)

__device__ __forceinline__ h2 bch2(float f) { return __builtin_bit_cast(h2, f); }

// ---------------- Kernel 0: pack w1 into half2 pairs (w[2m], w[2m+1]) ----------------
__global__ __launch_bounds__(256) void k_prep(const float* __restrict__ w1,
                                              float* __restrict__ whb) {
  const int idx = threadIdx.x + blockIdx.x * 256;
  if (idx >= (O1 * C1) * (KK1 / 2)) return;
  const int oc = idx / (KK1 / 2);
  const int m  = idx - oc * (KK1 / 2);
  h2 v;
  v.x = (_Float16)w1[oc * KK1 + 2 * m];
  v.y = (_Float16)w1[oc * KK1 + 2 * m + 1];
  whb[idx] = __builtin_bit_cast(float, v);
}

// ---------------- Kernel 1: FUSED tropical conv1(min)+pool2 -> conv2(max)+pool2 ----------
// v6 = round-2 v2 exactly, except the mc-loop is FULLY unrolled: lets the
// scheduler hoist all 20 ds_read_b128 per channel ahead of the 960-op compute
// burst (lgkm batching). v3 (more blocks) and v5 (2 outputs/thread) both
// regressed; occupancy is pinned ~25% regardless, so latency must be hidden
// by in-wave ILP, not residency.
#define TILE2 127
#define NT12 16
#define DW12 295      // staged x pair-count: max read elem idx 2*(255+36)+7 = 589 = 2*294+1

__global__ __launch_bounds__(256) void k_conv12(const float* __restrict__ x,
                                                const float* __restrict__ whb,
                                                const float* __restrict__ w2,
                                                _Float16* __restrict__ p2h) {
  __shared__ float AB[C1][2 * DW12 + 2];
  __shared__ float ps[O1][256];
  __shared__ float w2s[O2 * O1 * KK2];   // 288 floats
  const int tile = blockIdx.x;           // 0..15
  const int b    = blockIdx.y;           // 0..63
  const int pj0  = 2 * TILE2 * tile;     // pooled-conv1 base index (254*tile)
  const int T0   = 2 * pj0;              // x-domain base
  const int tid  = threadIdx.x;

  for (int idx = tid; idx < O2 * O1 * KK2; idx += 256) w2s[idx] = w2[idx];
  for (int q = tid; q < C1 * DW12; q += 256) {
    const int c = q / DW12;
    const int d = q - c * DW12;
    const int E = T0 + 2 * d - PAD1;
    const float* xc = x + ((size_t)b * C1 + c) * LIN;
    float f0 = 0.f, f1 = 0.f, f2 = 0.f;
    if ((unsigned)E < LIN) f0 = xc[E];
    if ((unsigned)(E + 1) < LIN) f1 = xc[E + 1];
    if ((unsigned)(E + 2) < LIN) f2 = xc[E + 2];
    h2 A; A.x = (_Float16)f0; A.y = (_Float16)f1;
    h2 Bv; Bv.x = (_Float16)f1; Bv.y = (_Float16)f2;
    AB[c][2 * d]     = __builtin_bit_cast(float, A);
    AB[c][2 * d + 1] = __builtin_bit_cast(float, Bv);
  }
  __syncthreads();

  // ---- conv1 (min-plus) + avgpool2 for pooled position pj0 + jj ----
  const int jj = tid;

  float s0 = 0.f, s1 = 0.f, s2 = 0.f, s3 = 0.f, s4 = 0.f, s5 = 0.f;

#pragma unroll
  for (int c = 0; c < C1; ++c) {
    h2 aA[O1], aB[O1];
#pragma unroll
    for (int o = 0; o < O1; ++o) {
      aA[o].x = BIGH; aA[o].y = BIGH;
      aB[o].x = BIGH; aB[o].y = BIGH;
    }
#pragma unroll
    for (int mc = 0; mc < 10; ++mc) {      // m = mc*4 .. mc*4+3
      float4 xv0 = *(const float4*)&AB[c][2 * (jj + mc * 4)];
      float4 xv1 = *(const float4*)&AB[c][2 * (jj + mc * 4) + 4];
      h2 A0 = bch2(xv0.x), B0 = bch2(xv0.y);
      h2 A1 = bch2(xv0.z), B1 = bch2(xv0.w);
      h2 A2 = bch2(xv1.x), B2 = bch2(xv1.y);
      h2 A3 = bch2(xv1.z), B3 = bch2(xv1.w);
#pragma unroll
      for (int o = 0; o < O1; ++o) {
        float4 wq = *(const float4*)&whb[(o * C1 + c) * (KK1 / 2) + mc * 4];
        h2 w0 = bch2(wq.x), w1v = bch2(wq.y), w2v = bch2(wq.z), w3v = bch2(wq.w);
        aA[o] = __builtin_elementwise_min(aA[o], A0 + w0);
        aB[o] = __builtin_elementwise_min(aB[o], B0 + w0);
        aA[o] = __builtin_elementwise_min(aA[o], A1 + w1v);
        aB[o] = __builtin_elementwise_min(aB[o], B1 + w1v);
        aA[o] = __builtin_elementwise_min(aA[o], A2 + w2v);
        aB[o] = __builtin_elementwise_min(aB[o], B2 + w2v);
        aA[o] = __builtin_elementwise_min(aA[o], A3 + w3v);
        aB[o] = __builtin_elementwise_min(aB[o], B3 + w3v);
      }
    }
    float r[O1];
#pragma unroll
    for (int o = 0; o < O1; ++o)
      r[o] = fminf((float)aA[o].x, (float)aA[o].y) + fminf((float)aB[o].x, (float)aB[o].y);
    s0 += r[0]; s1 += r[1]; s2 += r[2]; s3 += r[3]; s4 += r[4]; s5 += r[5];
  }
  ps[0][jj] = 0.5f * s0;
  ps[1][jj] = 0.5f * s1;
  ps[2][jj] = 0.5f * s2;
  ps[3][jj] = 0.5f * s3;
  ps[4][jj] = 0.5f * s4;
  ps[5][jj] = 0.5f * s5;
  __syncthreads();

  // ---- conv2 (max-plus, K=3) + avgpool2, straight from LDS ----
  const int j2i = tid & 127;             // local conv2 output
  const int ot  = tid >> 7;              // 0/1 -> o-range split
  const int j2  = TILE2 * tile + j2i;
  if (j2i < TILE2 && j2 < LP2) {
    const int lb = 2 * j2i;              // <= 252, +3 <= 255: in range
    float xv[O1][4];
#pragma unroll
    for (int c = 0; c < O1; ++c) {
      xv[c][0] = ps[c][lb];     xv[c][1] = ps[c][lb + 1];
      xv[c][2] = ps[c][lb + 2]; xv[c][3] = ps[c][lb + 3];
    }
#pragma unroll
    for (int oi = 0; oi < 8; ++oi) {
      const int o = ot * 8 + oi;
      float s = 0.f;
#pragma unroll
      for (int c = 0; c < O1; ++c) {
        float w0  = w2s[(o * O1 + c) * KK2 + 0];
        float w1v = w2s[(o * O1 + c) * KK2 + 1];
        float w2v = w2s[(o * O1 + c) * KK2 + 2];
        float m0 = fmaxf(fmaxf(xv[c][0] + w0, xv[c][1] + w1v), xv[c][2] + w2v);
        float m1 = fmaxf(fmaxf(xv[c][1] + w0, xv[c][2] + w1v), xv[c][3] + w2v);
        s += m0 + m1;
      }
      p2h[(size_t)b * NFLAT + o * LP2 + j2] = (_Float16)(0.5f * s);
    }
  }
}

// ---------------- Kernel 2: FC1 split-K via MFMA f16, KC=128, 512 threads ----------------
// LDS XOR swizzle (half-index ^= (row&7)<<3): kills the 16-way bank conflict the
// row-stride-256B layout had on ds_read_b128 (G4/T2). Applied on BOTH write and read.
#define KC2 128
#define NKC2 254
#define BSWZ(row, colh) ((colh) ^ (((row) & 7) << 3))

#define FC1_STEP(ks)                                                                     \
  {                                                                                      \
    float4 al = *(const float4*)(wp + (ks) * 32);                                        \
    float4 ah = *(const float4*)(wp + (ks) * 32 + 4);                                    \
    f16x8 A;                                                                             \
    A[0] = (_Float16)al.x; A[1] = (_Float16)al.y;                                        \
    A[2] = (_Float16)al.z; A[3] = (_Float16)al.w;                                        \
    A[4] = (_Float16)ah.x; A[5] = (_Float16)ah.y;                                        \
    A[6] = (_Float16)ah.z; A[7] = (_Float16)ah.w;                                        \
    _Pragma("unroll")                                                                    \
    for (int nt = 0; nt < 4; ++nt) {                                                     \
      const int brow = nt * 16 + m_l;                                                    \
      f16x8 Bf = *(const f16x8*)&bs[brow][BSWZ(brow, (ks) * 32 + q * 8)];                \
      acc[nt] = __builtin_amdgcn_mfma_f32_16x16x32_f16(A, Bf, acc[nt], 0, 0, 0);         \
    }                                                                                    \
  }

__global__ __launch_bounds__(512) void k_fc1(const _Float16* __restrict__ p2h,
                                             const float* __restrict__ w,
                                             _Float16* __restrict__ part) {
  __shared__ _Float16 bs[64][KC2];    // [b][k] swizzled, 16 KB
  const int kc  = blockIdx.x;
  const int k0  = kc * KC2;
  const int tid = threadIdx.x;

  // stage: 64 rows x 16 float4 = 1024 tasks, 2 per thread; zero-pad K tail
#pragma unroll
  for (int r = 0; r < 2; ++r) {
    const int task = tid + 512 * r;
    const int row  = task >> 4;          // 0..63
    const int c4   = task & 15;          // 0..15
    const int k    = k0 + c4 * 8;
    float4 v = {0.f, 0.f, 0.f, 0.f};
    if (k + 8 <= NFLAT) v = *(const float4*)&p2h[(size_t)row * NFLAT + k];
    *(float4*)&bs[row][BSWZ(row, c4 * 8)] = v;
  }
  __syncthreads();

  const int lane = tid & 63;
  const int wid  = tid >> 6;             // 0..7
  const int m_l  = lane & 15;
  const int q    = lane >> 4;            // 0..3
  const int m0   = wid * 16;

  int rowA = m0 + m_l;                   // 0..127; clamp pad rows
  if (rowA > H1 - 1) rowA = H1 - 1;
  const float* wp = w + (size_t)rowA * NFLAT + k0 + q * 8;

  f32x4 acc[4];
#pragma unroll
  for (int nt = 0; nt < 4; ++nt) acc[nt] = (f32x4){0.f, 0.f, 0.f, 0.f};

  if (k0 + KC2 <= NFLAT) {
    FC1_STEP(0) FC1_STEP(1) FC1_STEP(2) FC1_STEP(3)
  } else {                               // last block: only 64 valid k
    FC1_STEP(0) FC1_STEP(1)
  }

#pragma unroll
  for (int nt = 0; nt < 4; ++nt)
#pragma unroll
    for (int r = 0; r < 4; ++r) {
      const int i = m0 + q * 4 + r;
      if (i < H1)
        part[((size_t)kc * H1 + i) * 64 + nt * 16 + m_l] = (_Float16)acc[nt][r];
    }
}

// ---------------- Kernel 3: reduce ALL partials + bias + ReLU -> h1[120][64] ----------
__global__ __launch_bounds__(1024) void k_h1(const _Float16* __restrict__ part,
                                             const float* __restrict__ fc1_b,
                                             float* __restrict__ h1g) {
  __shared__ float red[1024];
  const int i   = blockIdx.x;            // 0..119
  const int tid = threadIdx.x;
  const int b   = tid & 63;
  const int sub = tid >> 6;              // 0..15
  float acc = 0.f;
  for (int kc = sub; kc < NKC2; kc += 16)
    acc += (float)part[((size_t)kc * H1 + i) * 64 + b];
  red[tid] = acc;
  __syncthreads();
  if (tid < 64) {
    float t = 0.f;
#pragma unroll
    for (int s2 = 0; s2 < 16; ++s2) t += red[b + 64 * s2];
    h1g[i * 64 + b] = fmaxf(t + fc1_b[i], 0.f);
  }
}

// ---------------- Kernel 4: FC2+ReLU, FC3 ----------------
__global__ __launch_bounds__(128) void k_head(const float* __restrict__ h1g,
                                              const float* __restrict__ fc2_w,
                                              const float* __restrict__ fc2_b,
                                              const float* __restrict__ fc3_w,
                                              const float* __restrict__ fc3_b,
                                              float* __restrict__ out) {
  __shared__ float h1s[H1];
  __shared__ float h2s[H2];
  const int b = blockIdx.x;
  const int tid = threadIdx.x;
  if (tid < H1) h1s[tid] = h1g[tid * 64 + b];
  __syncthreads();
  if (tid < H2) {
    float s = fc2_b[tid];
#pragma unroll 4
    for (int n = 0; n < H1; ++n) s += h1s[n] * fc2_w[tid * H1 + n];
    h2s[tid] = fmaxf(s, 0.f);
  }
  __syncthreads();
  if (tid < NOUT) {
    float s = fc3_b[tid];
#pragma unroll 4
    for (int n = 0; n < H2; ++n) s += h2s[n] * fc3_w[tid * H2 + n];
    out[b * NOUT + tid] = s;
  }
}

extern "C" void kernel_launch(void* const* d_in, const int* in_sizes, int n_in,
                              void* d_out, int out_size, void* d_ws, size_t ws_size,
                              hipStream_t stream) {
  const float* x     = (const float*)d_in[0];
  const float* w1    = (const float*)d_in[1];
  const float* w2    = (const float*)d_in[2];
  const float* fc1_w = (const float*)d_in[3];
  const float* fc1_b = (const float*)d_in[4];
  const float* fc2_w = (const float*)d_in[5];
  const float* fc2_b = (const float*)d_in[6];
  const float* fc3_w = (const float*)d_in[7];
  const float* fc3_b = (const float*)d_in[8];

  _Float16* p2h  = (_Float16*)d_ws;                               // 64*32448 h
  _Float16* part = p2h + (size_t)BB * NFLAT;                      // 254*120*64 h
  float*    h1g  = (float*)(part + (size_t)NKC2 * H1 * 64);       // 120*64 f
  float*    whb  = h1g + (size_t)H1 * 64;                         // 720 f
  float*    out  = (float*)d_out;

  hipLaunchKernelGGL(k_prep, dim3(3), dim3(256), 0, stream, w1, whb);
  hipLaunchKernelGGL(k_conv12, dim3(NT12, BB), dim3(256), 0, stream, x, whb, w2, p2h);
  hipLaunchKernelGGL(k_fc1, dim3(NKC2), dim3(512), 0, stream, p2h, fc1_w, part);
  hipLaunchKernelGGL(k_h1, dim3(H1), dim3(1024), 0, stream, part, fc1_b, h1g);
  hipLaunchKernelGGL(k_head, dim3(BB), dim3(128), 0, stream, h1g, fc2_w, fc2_b,
                     fc3_w, fc3_b, out);
}